// Round 10
// baseline (383.399 us; speedup 1.0000x reference)
//
#include <hip/hip_runtime.h>
#include <stdint.h>

#define B_     4
#define A_     9
#define H_     50
#define W_     76
#define N_     (H_ * W_ * A_)   // 34200
#define PRE_   6000
#define POST_  300
#define NBIN   16384
#define BINOFF 0xC000
#define NSEG   64
#define SKCAP  8192
#define ACTMAX 256
#define FXCAP  2048
#define NB_    94               // ceil(PRE_/64)
#define NBLK   64               // mega-kernel grid (co-resident on 256 CUs)

// generate_anchors(16) precomputed (exact, verified against the numpy code)
__constant__ float c_anchors[9][4] = {
    { -84.f,  -40.f,  99.f,  55.f},
    {-176.f,  -88.f, 191.f, 103.f},
    {-360.f, -184.f, 375.f, 199.f},
    { -56.f,  -56.f,  71.f,  71.f},
    {-120.f, -120.f, 135.f, 135.f},
    {-248.f, -248.f, 263.f, 263.f},
    { -36.f,  -80.f,  51.f,  95.f},
    { -80.f, -168.f,  95.f, 183.f},
    {-168.f, -344.f, 183.f, 359.f},
};

// composite key: (~score_bits)<<32 | n  — ascending key == descending score, ascending idx
__device__ __forceinline__ unsigned long long make_key(const float* __restrict__ scores,
                                                       int idx, int* pb) {
    int w = idx % W_;
    int h = (idx / W_) % H_;
    int a = (idx / (W_ * H_)) % A_;
    int b = idx / (W_ * H_ * A_);
    float s = scores[(((b * 2 * A_) + A_ + a) * H_ + h) * W_ + w];
    unsigned int sb = __float_as_uint(s);          // s >= 0 -> monotone bits
    unsigned int n  = (unsigned int)((h * W_ + w) * A_ + a);
    *pb = b;
    return (((unsigned long long)(~sb)) << 32) | (unsigned long long)n;
}

// scores in [0,1) -> top16 of key in [0xC080,0xFFFF]; clamp is monotone (exactness kept
// by full-key rank within bucket).
__device__ __forceinline__ int key_bin(unsigned long long key) {
    int bin = (int)(unsigned int)(key >> 48) - BINOFF;
    return bin < 0 ? 0 : bin;
}

// box decode exactly in the reference op order; no FMA contraction
__device__ __forceinline__ void compute_box(int b, unsigned int n,
                                            const float* __restrict__ deltas,
                                            const float* __restrict__ im_info,
                                            float box[4]) {
#pragma clang fp contract(off)
    int a   = (int)(n % A_);
    int pos = (int)(n / A_);
    int w   = pos % W_;
    int h   = pos / W_;
    float a0 = c_anchors[a][0] + (float)(w * 16);
    float a1 = c_anchors[a][1] + (float)(h * 16);
    float a2 = c_anchors[a][2] + (float)(w * 16);
    float a3 = c_anchors[a][3] + (float)(h * 16);
    float wa  = a2 - a0 + 1.f;
    float ha  = a3 - a1 + 1.f;
    float cxa = a0 + 0.5f * wa;
    float cya = a1 + 0.5f * ha;
    int base = ((b * 4 * A_ + a * 4) * H_ + h) * W_ + w;
    const int chs = H_ * W_;
    float dx = deltas[base];
    float dy = deltas[base + chs];
    float dw = deltas[base + 2 * chs];
    float dh = deltas[base + 3 * chs];
    float pcx = dx * wa + cxa;
    float pcy = dy * ha + cya;
    float pw  = expf(dw) * wa;
    float ph  = expf(dh) * ha;
    float x1 = pcx - 0.5f * pw;
    float y1 = pcy - 0.5f * ph;
    float x2 = pcx + 0.5f * pw;
    float y2 = pcy + 0.5f * ph;
    float imh = im_info[b * 3 + 0], imw = im_info[b * 3 + 1];
    x1 = fminf(fmaxf(x1, 0.f), imw - 1.f);
    x2 = fminf(fmaxf(x2, 0.f), imw - 1.f);
    y1 = fminf(fmaxf(y1, 0.f), imh - 1.f);
    y2 = fminf(fmaxf(y2, 0.f), imh - 1.f);
    box[0] = x1; box[1] = y1; box[2] = x2; box[3] = y2;
}

// device-scope one-shot grid barrier (slot used once per launch; bar pre-zeroed by memset)
__device__ __forceinline__ void gbar(unsigned int* bar, int slot) {
    __threadfence();                       // release this thread's prior writes
    __syncthreads();
    if (threadIdx.x == 0) {
        __hip_atomic_fetch_add(bar + slot, 1u, __ATOMIC_ACQ_REL, __HIP_MEMORY_SCOPE_AGENT);
        while (__hip_atomic_load(bar + slot, __ATOMIC_ACQUIRE, __HIP_MEMORY_SCOPE_AGENT)
               < (unsigned int)NBLK) {
            __builtin_amdgcn_s_sleep(1);
        }
    }
    __syncthreads();
    __threadfence();                       // acquire: subsequent reads see remote writes
}

__global__ __launch_bounds__(1024) void k_mega(
    const float* __restrict__ scores, const float* __restrict__ deltas,
    const float* __restrict__ im_info, float* __restrict__ out,
    unsigned int* bar, unsigned int* actcnt, unsigned int* segsum,
    unsigned int* actA, unsigned int* actB,
    unsigned int* hist, unsigned int* prefw,
    unsigned long long* skeys, float* sbx, unsigned long long* maskb) {

    const int tid  = threadIdx.x;
    const int bk   = blockIdx.x;             // 0..63
    const int gtid = bk * 1024 + tid;        // 0..65535
    const int lane = tid & 63;
    const int wid  = tid >> 6;               // 0..15

    __shared__ unsigned long long lk[FXCAP];               // P5 (16 KB)
    __shared__ float4 s_box[POST_ + 64];                   // P7
    __shared__ float  s_ar [POST_ + 64];
    __shared__ unsigned long long s_pend[2][16];
    __shared__ int s_cnt[2];
    __shared__ int s_final;

    // ---- P0: zero histogram (65536 words == grid threads exactly)
    hist[gtid] = 0u;
    gbar(bar, 0);

    // ---- P1: histogram
    for (int i = gtid; i < B_ * N_; i += NBLK * 1024) {
        int b; unsigned long long key = make_key(scores, i, &b);
        atomicAdd(&hist[b * NBIN + key_bin(key)], 1u);
    }
    gbar(bar, 1);

    // ---- P2: per-segment sums (one wave per (b,seg) task)
    {
        int gw = bk * 16 + wid;
        if (gw < B_ * NSEG) {
            int b = gw >> 6, seg = gw & 63;
            uint4 v = ((const uint4*)(hist + b * NBIN + seg * 256))[lane];
            unsigned int s = v.x + v.y + v.z + v.w;
#pragma unroll
            for (int off = 32; off > 0; off >>= 1) s += __shfl_down(s, off);
            if (lane == 0) segsum[b * NSEG + seg] = s;
        }
    }
    gbar(bar, 2);

    // ---- P3: global exclusive prefix + active-bucket list (one wave per task)
    {
        int gw = bk * 16 + wid;
        if (gw < B_ * NSEG) {
            int b = gw >> 6, seg = gw & 63;
            unsigned int sv = segsum[b * NSEG + lane];
            unsigned int inc = sv;
#pragma unroll
            for (int off = 1; off < 64; off <<= 1) {
                unsigned int t = __shfl_up(inc, off);
                if (lane >= off) inc += t;
            }
            unsigned int segbase = __shfl(inc - sv, seg);
            uint4 c = ((const uint4*)(hist + b * NBIN + seg * 256))[lane];
            unsigned int lsum = c.x + c.y + c.z + c.w;
            unsigned int li = lsum;
#pragma unroll
            for (int off = 1; off < 64; off <<= 1) {
                unsigned int t = __shfl_up(li, off);
                if (lane >= off) li += t;
            }
            unsigned int base = segbase + li - lsum;
            uint4 r;
            r.x = base;
            r.y = base + c.x;
            r.z = base + c.x + c.y;
            r.w = base + c.x + c.y + c.z;
            ((uint4*)(hist  + b * NBIN + seg * 256))[lane] = r;
            ((uint4*)(prefw + b * NBIN + seg * 256))[lane] = r;
            unsigned int cc[4] = {c.x, c.y, c.z, c.w};
            unsigned int rr[4] = {r.x, r.y, r.z, r.w};
            int bin0 = seg * 256 + lane * 4;
#pragma unroll
            for (int q = 0; q < 4; ++q) {
                if (cc[q] > 0 && rr[q] < (unsigned int)PRE_) {
                    unsigned int pos = atomicAdd(&actcnt[b], 1u);
                    if (pos < ACTMAX) {
                        actA[b * ACTMAX + pos] = rr[q];
                        actB[b * ACTMAX + pos] = ((unsigned int)(bin0 + q) << 16) | (cc[q] & 0xffffu);
                    }
                }
            }
        }
    }
    gbar(bar, 3);

    // ---- P4: scatter keys to bucket slot ranges (arrival order; fixed by P5)
    for (int i = gtid; i < B_ * N_; i += NBLK * 1024) {
        int b; unsigned long long key = make_key(scores, i, &b);
        int bin = key_bin(key);
        if (hist[b * NBIN + bin] < (unsigned int)PRE_) {
            unsigned int slot = atomicAdd(&prefw[b * NBIN + bin], 1u);
            if (slot < SKCAP) skeys[b * SKCAP + slot] = key;
        }
    }
    gbar(bar, 4);

    // ---- P5: per-bucket exact rank + box decode into final sorted slot
    for (int T = bk; T < B_ * ACTMAX; T += NBLK) {       // 16 iterations, block-uniform
        int b = T >> 8, j = T & 255;
        unsigned int nact = actcnt[b];
        if (nact > ACTMAX) nact = ACTMAX;
        if ((unsigned int)j < nact) {
            unsigned int start = actA[b * ACTMAX + j];
            unsigned int ab    = actB[b * ACTMAX + j];
            unsigned int m     = ab & 0xffffu;
            if (start + m > SKCAP) m = SKCAP - start;
            if (m > FXCAP) m = FXCAP;
            for (unsigned int i2 = tid; i2 < m; i2 += 1024) lk[i2] = skeys[b * SKCAP + start + i2];
            __syncthreads();
            float4* sb4 = (float4*)sbx;
            for (unsigned int e = tid; e < m; e += 1024) {
                unsigned long long k = lk[e];
                unsigned int rnk = 0;
                for (unsigned int i2 = 0; i2 < m; ++i2) rnk += (lk[i2] < k) ? 1u : 0u;
                unsigned int pos = start + rnk;
                if (pos < (unsigned int)PRE_) {
                    unsigned int n = (unsigned int)(k & 0xffffffffull);
                    float box[4];
                    compute_box(b, n, deltas, im_info, box);
                    sb4[b * PRE_ + pos] = make_float4(box[0], box[1], box[2], box[3]);
                }
            }
            __syncthreads();
        }
    }
    gbar(bar, 5);

    // ---- P6: per-64-block intra suppression masks (one wave per (b,blk) task)
    {
        int gw = bk * 16 + wid;
        if (gw < B_ * NB_) {
            int b = gw / NB_, blk = gw % NB_;
            const float4* bb = (const float4*)sbx + b * PRE_;
            int idx = blk * 64 + lane;
            float4 v = bb[idx < PRE_ ? idx : PRE_ - 1];
            float area = ((v.z - v.x) + 1.f) * ((v.w - v.y) + 1.f);
            unsigned long long myrow = 0ull;
            for (int i = 0; i < 64; ++i) {
                float ix1 = __shfl(v.x, i), iy1 = __shfl(v.y, i);
                float ix2 = __shfl(v.z, i), iy2 = __shfl(v.w, i);
                float iar = __shfl(area, i);
                float iw = fminf(v.z, ix2) - fmaxf(v.x, ix1) + 1.f;
                float ih = fminf(v.w, iy2) - fmaxf(v.y, iy1) + 1.f;
                iw = fmaxf(iw, 0.f); ih = fmaxf(ih, 0.f);
                float inter = iw * ih;
                float iou = inter / ((area + iar) - inter);
                unsigned long long bal = __ballot((lane > i) && (iou > 0.7f));
                if (lane == i) myrow = bal;
            }
            maskb[(b * NB_ + blk) * 64 + lane] = myrow;
        }
    }
    gbar(bar, 6);

    // ---- P7: exact greedy NMS (round-7 pipelined structure), blocks 0..3 only
    if (bk >= B_) return;
    {
        int b = bk;
        int wave = wid;
        if (tid < 32) ((unsigned long long*)s_pend)[tid] = 0ull;
        if (tid < 2) s_cnt[tid] = 0;
        if (tid == 0) s_final = 0;
        __syncthreads();

        const float4* bb = (const float4*)sbx + b * PRE_;
        float* ob = out + b * POST_ * 5;

        float4 vme;
        unsigned long long rowme = 0ull;
        if (wave == 0) {
            vme = bb[lane];
            rowme = maskb[(b * NB_ + 0) * 64 + lane];
        } else {
            vme = bb[64 + lane];
        }

        for (int k = 0; k < NB_; ++k) {
            int Cm1 = s_cnt[(k + 1) & 1];
            if (Cm1 >= POST_) break;
            if (wave == 0) {
                int idx = k * 64 + lane;
                bool valid = idx < PRE_;
                float4 v = vme;
                unsigned long long row = rowme;
                if (k + 1 < NB_) {
                    int nidx = (k + 1) * 64 + lane;
                    vme = bb[nidx < PRE_ ? nidx : PRE_ - 1];
                    rowme = maskb[(b * NB_ + k + 1) * 64 + lane];
                }
                float area = ((v.z - v.x) + 1.f) * ((v.w - v.y) + 1.f);
                int Cm2 = s_cnt[k & 1];
                bool sup = !valid;
                for (int kk = Cm2; kk < Cm1; ++kk) {
                    float4 kb = s_box[kk];
                    float iw = fminf(v.z, kb.z) - fmaxf(v.x, kb.x) + 1.f;
                    float ih = fminf(v.w, kb.w) - fmaxf(v.y, kb.y) + 1.f;
                    iw = fmaxf(iw, 0.f); ih = fmaxf(ih, 0.f);
                    float inter = iw * ih;
                    float iou = inter / ((area + s_ar[kk]) - inter);
                    sup = sup | (iou > 0.7f);
                }
                unsigned long long supm = __ballot(sup);
                const unsigned long long* pnd = s_pend[k & 1];
#pragma unroll
                for (int w2 = 1; w2 < 16; ++w2) supm |= pnd[w2];
                unsigned int rlo = (unsigned int)row;
                unsigned int rhi = (unsigned int)(row >> 32);
                unsigned long long alive = ~supm;
                unsigned long long keepm = 0ull;
                while (alive) {
                    int i = __builtin_ctzll(alive);
                    keepm |= (1ull << i);
                    alive &= ~(1ull << i);
                    unsigned long long mlo = (unsigned int)__builtin_amdgcn_readlane((int)rlo, i);
                    unsigned long long mhi = (unsigned int)__builtin_amdgcn_readlane((int)rhi, i);
                    alive &= ~((mhi << 32) | mlo);
                }
                if ((keepm >> lane) & 1ull) {
                    int my = Cm1 + __builtin_popcountll(keepm & ((1ull << lane) - 1ull));
                    s_box[my] = v;
                    s_ar [my] = area;
                    if (my < POST_) {
                        ob[my * 5 + 0] = (float)b;
                        ob[my * 5 + 1] = v.x; ob[my * 5 + 2] = v.y;
                        ob[my * 5 + 3] = v.z; ob[my * 5 + 4] = v.w;
                    }
                }
                if (lane == 0) {
                    int nc = Cm1 + __builtin_popcountll(keepm);
                    s_cnt[k & 1] = nc;
                    s_final = nc;
                }
            } else if (k + 1 < NB_) {
                int jdx = (k + 1) * 64 + lane;
                bool valid2 = jdx < PRE_;
                float4 v2 = vme;
                if (k + 2 < NB_) {
                    int nj = (k + 2) * 64 + lane;
                    vme = bb[nj < PRE_ ? nj : PRE_ - 1];
                }
                float area2 = ((v2.z - v2.x) + 1.f) * ((v2.w - v2.y) + 1.f);
                bool sup2 = !valid2;
                for (int kk = wave - 1; kk < Cm1; kk += 15) {
                    float4 kb = s_box[kk];
                    float iw = fminf(v2.z, kb.z) - fmaxf(v2.x, kb.x) + 1.f;
                    float ih = fminf(v2.w, kb.w) - fmaxf(v2.y, kb.y) + 1.f;
                    iw = fmaxf(iw, 0.f); ih = fmaxf(ih, 0.f);
                    float inter = iw * ih;
                    float iou = inter / ((area2 + s_ar[kk]) - inter);
                    sup2 = sup2 | (iou > 0.7f);
                }
                unsigned long long bal = __ballot(sup2);
                if (lane == 0) s_pend[(k + 1) & 1][wave] = bal;
            }
            __syncthreads();
        }
        __syncthreads();
        int kept = s_final;
        int start = kept < POST_ ? kept : POST_;
        for (int r = start + tid; r < POST_; r += 1024) {
            ob[r * 5 + 0] = (float)b;
            ob[r * 5 + 1] = 0.f; ob[r * 5 + 2] = 0.f;
            ob[r * 5 + 3] = 0.f; ob[r * 5 + 4] = 0.f;
        }
    }
}

extern "C" void kernel_launch(void* const* d_in, const int* in_sizes, int n_in,
                              void* d_out, int out_size, void* d_ws, size_t ws_size,
                              hipStream_t stream) {
    const float* scores  = (const float*)d_in[0];
    const float* deltas  = (const float*)d_in[1];
    const float* im_info = (const float*)d_in[2];
    float* out = (float*)d_out;

    // workspace layout. maskb OVERLAPS hist (hist dead after P4; P6 writes after P5 barrier).
    char* ws = (char*)d_ws;
    unsigned int*       bar     = (unsigned int*)      (ws);             //      32 (8 slots)
    unsigned int*       actcnt  = (unsigned int*)      (ws + 32);        //      16
    unsigned int*       segsum  = (unsigned int*)      (ws + 64);        //   1,024
    unsigned int*       actA    = (unsigned int*)      (ws + 4096);      //   4,096
    unsigned int*       actB    = (unsigned int*)      (ws + 8192);      //   4,096
    unsigned int*       hist    = (unsigned int*)      (ws + 12288);     // 262,144
    unsigned long long* maskb   = (unsigned long long*)(ws + 12288);     // 192,512 (reuse)
    unsigned int*       prefw   = (unsigned int*)      (ws + 274432);    // 262,144
    unsigned long long* skeys   = (unsigned long long*)(ws + 536576);    // 262,144
    float*              sbx     = (float*)             (ws + 798720);    // 384,000

    hipMemsetAsync(ws, 0, 64, stream);   // barrier slots + actcnt

    k_mega<<<NBLK, 1024, 0, stream>>>(scores, deltas, im_info, out,
                                      bar, actcnt, segsum, actA, actB,
                                      hist, prefw, skeys, sbx, maskb);
}

// Round 11
// 210.287 us; speedup vs baseline: 1.8232x; 1.8232x over previous
//
#include <hip/hip_runtime.h>
#include <stdint.h>

#define B_     4
#define A_     9
#define H_     50
#define W_     76
#define HW_    (H_ * W_)         // 3800
#define N_     (HW_ * A_)        // 34200
#define PRE_   6000
#define POST_  300
#define NBIN   16384
#define BINOFF 0xC000
#define SKCAP  8192
#define ACTMAX 512
#define KCAP   256               // register-rank cap (mean bucket ~134, +10 sigma)
#define NB_    94                // ceil(PRE_/64)

// generate_anchors(16) precomputed (exact, verified against the numpy code)
__constant__ float c_anchors[9][4] = {
    { -84.f,  -40.f,  99.f,  55.f},
    {-176.f,  -88.f, 191.f, 103.f},
    {-360.f, -184.f, 375.f, 199.f},
    { -56.f,  -56.f,  71.f,  71.f},
    {-120.f, -120.f, 135.f, 135.f},
    {-248.f, -248.f, 263.f, 263.f},
    { -36.f,  -80.f,  51.f,  95.f},
    { -80.f, -168.f,  95.f, 183.f},
    {-168.f, -344.f, 183.f, 359.f},
};

// box decode exactly in the reference op order; no FMA contraction
__device__ __forceinline__ void compute_box(int b, unsigned int n,
                                            const float* __restrict__ deltas,
                                            const float* __restrict__ im_info,
                                            float box[4]) {
#pragma clang fp contract(off)
    int a   = (int)(n % A_);
    int pos = (int)(n / A_);
    int w   = pos % W_;
    int h   = pos / W_;
    float a0 = c_anchors[a][0] + (float)(w * 16);
    float a1 = c_anchors[a][1] + (float)(h * 16);
    float a2 = c_anchors[a][2] + (float)(w * 16);
    float a3 = c_anchors[a][3] + (float)(h * 16);
    float wa  = a2 - a0 + 1.f;
    float ha  = a3 - a1 + 1.f;
    float cxa = a0 + 0.5f * wa;
    float cya = a1 + 0.5f * ha;
    int base = ((b * 4 * A_ + a * 4) * H_ + h) * W_ + w;
    const int chs = HW_;
    float dx = deltas[base];
    float dy = deltas[base + chs];
    float dw = deltas[base + 2 * chs];
    float dh = deltas[base + 3 * chs];
    float pcx = dx * wa + cxa;
    float pcy = dy * ha + cya;
    float pw  = expf(dw) * wa;
    float ph  = expf(dh) * ha;
    float x1 = pcx - 0.5f * pw;
    float y1 = pcy - 0.5f * ph;
    float x2 = pcx + 0.5f * pw;
    float y2 = pcy + 0.5f * ph;
    float imh = im_info[b * 3 + 0], imw = im_info[b * 3 + 1];
    x1 = fminf(fmaxf(x1, 0.f), imw - 1.f);
    x2 = fminf(fmaxf(x2, 0.f), imw - 1.f);
    y1 = fminf(fmaxf(y1, 0.f), imh - 1.f);
    y2 = fminf(fmaxf(y2, 0.f), imh - 1.f);
    box[0] = x1; box[1] = y1; box[2] = x2; box[3] = y2;
}

// ---- the whole ProposalLayer per image in ONE workgroup (only __syncthreads) ----
__global__ __launch_bounds__(1024) void k_all(
    const float* __restrict__ scores, const float* __restrict__ deltas,
    const float* __restrict__ im_info, float* __restrict__ out,
    unsigned long long* __restrict__ skeys, unsigned long long* __restrict__ maskg) {

    const int b    = blockIdx.x;
    const int tid  = threadIdx.x;
    const int lane = tid & 63;
    const int wid  = tid >> 6;               // 0..15

    // LDS: 96256B region overlaid {hist uint[16384] | boxes float4[6016]}
    __shared__ __align__(16) char s_big[6016 * 16];
    unsigned int* LHIST = (unsigned int*)s_big;
    float4*       SBOX  = (float4*)s_big;
    __shared__ float4 s_kbox[POST_ + 64];
    __shared__ float  s_kar [POST_ + 64];
    __shared__ unsigned long long s_pend[2][16];
    __shared__ unsigned int s_actA[ACTMAX];
    __shared__ unsigned int s_actB[ACTMAX];
    __shared__ unsigned int s_wsum[16];
    __shared__ int s_actn, s_binhi, s_cnt[2], s_final;

    // ---- P0: zero LDS hist + scalars
    for (int i = tid; i < NBIN; i += 1024) LHIST[i] = 0u;
    if (tid == 0) { s_actn = 0; s_binhi = 0; }
    __syncthreads();

    // ---- P1: LDS histogram of key top-16 bins (coalesced score reads)
    const float* sc = scores + (size_t)((b * 2 * A_) + A_) * HW_;
    for (int i = tid; i < N_; i += 1024) {
        unsigned int sb = __float_as_uint(sc[i]);
        int bin = (int)((~sb) >> 16) - BINOFF;
        if (bin < 0) bin = 0;
        atomicAdd(&LHIST[bin], 1u);
    }
    __syncthreads();

    // ---- P2: in-place exclusive prefix (16 bins/thread, hierarchical shfl scan),
    //          active-bucket list, bin_hi (prefix monotone -> active bins = [0, bin_hi])
    {
        int base0 = tid * 16;
        unsigned int sum = 0;
        for (int q = 0; q < 16; ++q) sum += LHIST[base0 + q];
        unsigned int inc = sum;
#pragma unroll
        for (int off = 1; off < 64; off <<= 1) {
            unsigned int t = __shfl_up(inc, off);
            if (lane >= off) inc += t;
        }
        if (lane == 63) s_wsum[wid] = inc;
        __syncthreads();
        unsigned int wbase = 0;
        for (int wq = 0; wq < wid; ++wq) wbase += s_wsum[wq];
        unsigned int run = wbase + inc - sum;     // exclusive prefix of this thread's bins
        int mybinhi = -1;
        for (int q = 0; q < 16; ++q) {
            unsigned int c = LHIST[base0 + q];
            LHIST[base0 + q] = run;
            if (run < (unsigned int)PRE_) {
                mybinhi = base0 + q;
                if (c > 0) {
                    int pos = atomicAdd(&s_actn, 1);
                    if (pos < ACTMAX) {
                        s_actA[pos] = run;
                        s_actB[pos] = ((unsigned int)(base0 + q) << 16) | (c & 0xffffu);
                    }
                }
            }
            run += c;
        }
        if (mybinhi >= 0) atomicMax(&s_binhi, mybinhi);
    }
    __syncthreads();

    // ---- P3: scatter keys of active bins to global slot ranges (arrival order)
    {
        int binhi = s_binhi;
        for (int i = tid; i < N_; i += 1024) {
            unsigned int sb = __float_as_uint(sc[i]);
            int bin = (int)((~sb) >> 16) - BINOFF;
            if (bin < 0) bin = 0;
            if (bin <= binhi) {
                unsigned int slot = atomicAdd(&LHIST[bin], 1u);
                if (slot < SKCAP) {
                    int a = i / HW_, r = i - a * HW_;
                    unsigned int n = (unsigned int)(r * A_ + a);
                    skeys[b * SKCAP + slot] =
                        (((unsigned long long)(~sb)) << 32) | (unsigned long long)n;
                }
            }
        }
    }
    __threadfence_block();
    __syncthreads();
    // LHIST dead from here; s_big becomes SBOX.

    // ---- P4: per-wave bucket rank (in registers) + decode into final sorted LDS slot
    {
        int nact = s_actn; if (nact > ACTMAX) nact = ACTMAX;
        for (int t = wid; t < nact; t += 16) {
            unsigned int start = s_actA[t];
            unsigned int m     = s_actB[t] & 0xffffu;
            if (start + m > SKCAP) m = SKCAP - start;
            const unsigned long long* kb = skeys + b * SKCAP + start;
            if (m <= KCAP) {
                unsigned long long kreg[4];
                unsigned int rnk[4];
#pragma unroll
                for (int q = 0; q < 4; ++q) {
                    unsigned int e = (unsigned int)lane + q * 64u;
                    kreg[q] = (e < m) ? kb[e] : ~0ull;
                    rnk[q] = 0;
                }
#pragma unroll
                for (int q2 = 0; q2 < 4; ++q2) {
                    int base2 = q2 * 64;
                    if (base2 >= (int)m) break;
                    unsigned long long kq = kreg[q2];
                    int lim = (int)m - base2; if (lim > 64) lim = 64;
                    for (int l = 0; l < lim; ++l) {
                        unsigned long long ki = __shfl(kq, l);
#pragma unroll
                        for (int q = 0; q < 4; ++q) rnk[q] += (ki < kreg[q]) ? 1u : 0u;
                    }
                }
#pragma unroll
                for (int q = 0; q < 4; ++q) {
                    unsigned int e = (unsigned int)lane + q * 64u;
                    if (e < m) {
                        unsigned int pos = start + rnk[q];
                        if (pos < (unsigned int)PRE_) {
                            unsigned int n = (unsigned int)(kreg[q] & 0xffffffffull);
                            float box[4];
                            compute_box(b, n, deltas, im_info, box);
                            SBOX[pos] = make_float4(box[0], box[1], box[2], box[3]);
                        }
                    }
                }
            } else {   // correct fallback for pathological bucket sizes (never hit here)
                for (unsigned int e = lane; e < m; e += 64) {
                    unsigned long long k = kb[e];
                    unsigned int r = 0;
                    for (unsigned int i2 = 0; i2 < m; ++i2) r += (kb[i2] < k) ? 1u : 0u;
                    unsigned int pos = start + r;
                    if (pos < (unsigned int)PRE_) {
                        unsigned int n = (unsigned int)(k & 0xffffffffull);
                        float box[4];
                        compute_box(b, n, deltas, im_info, box);
                        SBOX[pos] = make_float4(box[0], box[1], box[2], box[3]);
                    }
                }
            }
        }
    }
    __syncthreads();

    // ---- P5: per-64-block intra suppression masks (one wave per block-task)
    for (int blk = wid; blk < NB_; blk += 16) {
        int idx = blk * 64 + lane;
        float4 v = SBOX[idx < PRE_ ? idx : PRE_ - 1];
        float area = ((v.z - v.x) + 1.f) * ((v.w - v.y) + 1.f);
        unsigned long long myrow = 0ull;
        for (int i = 0; i < 64; ++i) {
            float ix1 = __shfl(v.x, i), iy1 = __shfl(v.y, i);
            float ix2 = __shfl(v.z, i), iy2 = __shfl(v.w, i);
            float iar = __shfl(area, i);
            float iw = fminf(v.z, ix2) - fmaxf(v.x, ix1) + 1.f;
            float ih = fminf(v.w, iy2) - fmaxf(v.y, iy1) + 1.f;
            iw = fmaxf(iw, 0.f); ih = fmaxf(ih, 0.f);
            float inter = iw * ih;
            float iou = inter / ((area + iar) - inter);
            unsigned long long bal = __ballot((lane > i) && (iou > 0.7f));
            if (lane == i) myrow = bal;
        }
        maskg[(b * NB_ + blk) * 64 + lane] = myrow;
    }
    __threadfence_block();
    __syncthreads();

    // ---- P6: exact greedy NMS (proven round-7 pipelined structure; LDS candidates)
    {
        float* ob = out + b * POST_ * 5;
        int wave = wid;
        if (tid < 32) ((unsigned long long*)s_pend)[tid] = 0ull;
        if (tid < 2) s_cnt[tid] = 0;
        if (tid == 0) s_final = 0;
        __syncthreads();

        for (int k = 0; k < NB_; ++k) {
            int Cm1 = s_cnt[(k + 1) & 1];         // kept count through block k-1
            if (Cm1 >= POST_) break;
            if (wave == 0) {
                int idx = k * 64 + lane;
                bool valid = idx < PRE_;
                float4 v = SBOX[valid ? idx : PRE_ - 1];
                unsigned long long row = maskg[(b * NB_ + k) * 64 + lane];
                float area = ((v.z - v.x) + 1.f) * ((v.w - v.y) + 1.f);
                int Cm2 = s_cnt[k & 1];           // kept count through block k-2
                bool sup = !valid;
                for (int kk = Cm2; kk < Cm1; ++kk) {   // delta: keeps added by block k-1
                    float4 kb = s_kbox[kk];
                    float iw = fminf(v.z, kb.z) - fmaxf(v.x, kb.x) + 1.f;
                    float ih = fminf(v.w, kb.w) - fmaxf(v.y, kb.y) + 1.f;
                    iw = fmaxf(iw, 0.f); ih = fmaxf(ih, 0.f);
                    float inter = iw * ih;
                    float iou = inter / ((area + s_kar[kk]) - inter);
                    sup = sup | (iou > 0.7f);
                }
                unsigned long long supm = __ballot(sup);
                const unsigned long long* pnd = s_pend[k & 1];
#pragma unroll
                for (int w2 = 1; w2 < 16; ++w2) supm |= pnd[w2];
                unsigned int rlo = (unsigned int)row;
                unsigned int rhi = (unsigned int)(row >> 32);
                unsigned long long alive = ~supm;
                unsigned long long keepm = 0ull;
                while (alive) {
                    int i = __builtin_ctzll(alive);     // uniform across wave 0
                    keepm |= (1ull << i);
                    alive &= ~(1ull << i);
                    unsigned long long mlo = (unsigned int)__builtin_amdgcn_readlane((int)rlo, i);
                    unsigned long long mhi = (unsigned int)__builtin_amdgcn_readlane((int)rhi, i);
                    alive &= ~((mhi << 32) | mlo);
                }
                if ((keepm >> lane) & 1ull) {
                    int my = Cm1 + __builtin_popcountll(keepm & ((1ull << lane) - 1ull));
                    s_kbox[my] = v;
                    s_kar [my] = area;
                    if (my < POST_) {
                        ob[my * 5 + 0] = (float)b;
                        ob[my * 5 + 1] = v.x; ob[my * 5 + 2] = v.y;
                        ob[my * 5 + 3] = v.z; ob[my * 5 + 4] = v.w;
                    }
                }
                if (lane == 0) {
                    int nc = Cm1 + __builtin_popcountll(keepm);
                    s_cnt[k & 1] = nc;
                    s_final = nc;
                }
            } else if (k + 1 < NB_) {
                // phase-a for block k+1 vs kept[0..Cm1) (gap = wave0's delta next iter)
                int jdx = (k + 1) * 64 + lane;
                bool valid2 = jdx < PRE_;
                float4 v2 = SBOX[valid2 ? jdx : PRE_ - 1];
                float area2 = ((v2.z - v2.x) + 1.f) * ((v2.w - v2.y) + 1.f);
                bool sup2 = !valid2;
                for (int kk = wave - 1; kk < Cm1; kk += 15) {
                    float4 kb = s_kbox[kk];
                    float iw = fminf(v2.z, kb.z) - fmaxf(v2.x, kb.x) + 1.f;
                    float ih = fminf(v2.w, kb.w) - fmaxf(v2.y, kb.y) + 1.f;
                    iw = fmaxf(iw, 0.f); ih = fmaxf(ih, 0.f);
                    float inter = iw * ih;
                    float iou = inter / ((area2 + s_kar[kk]) - inter);
                    sup2 = sup2 | (iou > 0.7f);
                }
                unsigned long long bal = __ballot(sup2);
                if (lane == 0) s_pend[(k + 1) & 1][wave] = bal;
            }
            __syncthreads();
        }
        __syncthreads();
        int kept = s_final;
        int start = kept < POST_ ? kept : POST_;
        for (int r = start + tid; r < POST_; r += 1024) {
            ob[r * 5 + 0] = (float)b;
            ob[r * 5 + 1] = 0.f; ob[r * 5 + 2] = 0.f;
            ob[r * 5 + 3] = 0.f; ob[r * 5 + 4] = 0.f;
        }
    }
}

extern "C" void kernel_launch(void* const* d_in, const int* in_sizes, int n_in,
                              void* d_out, int out_size, void* d_ws, size_t ws_size,
                              hipStream_t stream) {
    const float* scores  = (const float*)d_in[0];
    const float* deltas  = (const float*)d_in[1];
    const float* im_info = (const float*)d_in[2];
    float* out = (float*)d_out;

    char* ws = (char*)d_ws;
    unsigned long long* skeys = (unsigned long long*)(ws);            // 262,144
    unsigned long long* maskg = (unsigned long long*)(ws + 262144);   // 192,512

    k_all<<<B_, 1024, 0, stream>>>(scores, deltas, im_info, out, skeys, maskg);
}

// Round 12
// 125.112 us; speedup vs baseline: 3.0645x; 1.6808x over previous
//
#include <hip/hip_runtime.h>
#include <stdint.h>

#define B_     4
#define A_     9
#define H_     50
#define W_     76
#define HW_    (H_ * W_)         // 3800
#define N_     (HW_ * A_)        // 34200
#define PRE_   6000
#define POST_  300
#define NBIN   16384
#define BINOFF 0xC000
#define SKCAP  8192
#define ACTMAX 256
#define FXCAP  2048
#define NB_    94               // ceil(PRE_/64)

// generate_anchors(16) precomputed (exact, verified against the numpy code)
__constant__ float c_anchors[9][4] = {
    { -84.f,  -40.f,  99.f,  55.f},
    {-176.f,  -88.f, 191.f, 103.f},
    {-360.f, -184.f, 375.f, 199.f},
    { -56.f,  -56.f,  71.f,  71.f},
    {-120.f, -120.f, 135.f, 135.f},
    {-248.f, -248.f, 263.f, 263.f},
    { -36.f,  -80.f,  51.f,  95.f},
    { -80.f, -168.f,  95.f, 183.f},
    {-168.f, -344.f, 183.f, 359.f},
};

// scores in [0,1) -> bin = top16(~score_bits) - 0xC000, clamped (monotone; exactness is
// restored by full-key rank within bucket in k_fixup).
__device__ __forceinline__ int sb_bin(unsigned int sb) {
    int bin = (int)((~sb) >> 16) - BINOFF;
    return bin < 0 ? 0 : bin;
}

// ---- kernel 1: histogram of score bins (direct coalesced score reads)
__global__ void k_hist(const float* __restrict__ scores,
                       unsigned int* __restrict__ hist) {
    int b = blockIdx.y;
    int i = blockIdx.x * 256 + threadIdx.x;
    if (i >= N_) return;
    const float* sc = scores + (size_t)((b * 2 * A_) + A_) * HW_;
    unsigned int sb = __float_as_uint(sc[i]);
    atomicAdd(&hist[b * NBIN + sb_bin(sb)], 1u);
}

// ---- kernel 2: full 16384-bin exclusive prefix in ONE block/image (coalesced uint4),
//      writes static prefix (hist), working prefix (prefw), active buckets, actcnt.
__global__ __launch_bounds__(1024) void k_prefix(unsigned int* __restrict__ hist,
                                                 unsigned int* __restrict__ prefw,
                                                 unsigned int* __restrict__ actA,
                                                 unsigned int* __restrict__ actB,
                                                 unsigned int* __restrict__ actcnt) {
    int b = blockIdx.x, tid = threadIdx.x;
    int lane = tid & 63, wid = tid >> 6;
    __shared__ unsigned int s_ws[64];       // (pass,wave) totals, bin-order p*16+wid
    __shared__ unsigned int s_aA[ACTMAX];
    __shared__ unsigned int s_aB[ACTMAX];
    __shared__ int s_actn;
    if (tid == 0) s_actn = 0;

    uint4* h4 = (uint4*)(hist + b * NBIN);
    uint4* p4 = (uint4*)(prefw + b * NBIN);
    uint4 c[4];
    unsigned int tsum[4], inc[4];
#pragma unroll
    for (int p = 0; p < 4; ++p) {
        c[p] = h4[p * 1024 + tid];
        tsum[p] = c[p].x + c[p].y + c[p].z + c[p].w;
        unsigned int v = tsum[p];
#pragma unroll
        for (int off = 1; off < 64; off <<= 1) {
            unsigned int t = __shfl_up(v, off);
            if (lane >= off) v += t;
        }
        inc[p] = v;                          // wave-inclusive scan of tsum
        if (lane == 63) s_ws[p * 16 + wid] = v;
    }
    __syncthreads();
    if (wid == 0) {                          // exclusive scan of the 64 totals
        unsigned int v = s_ws[lane];
        unsigned int s = v;
#pragma unroll
        for (int off = 1; off < 64; off <<= 1) {
            unsigned int t = __shfl_up(s, off);
            if (lane >= off) s += t;
        }
        s_ws[lane] = s - v;
    }
    __syncthreads();
#pragma unroll
    for (int p = 0; p < 4; ++p) {
        unsigned int base = s_ws[p * 16 + wid] + inc[p] - tsum[p];
        uint4 r;
        r.x = base;
        r.y = base + c[p].x;
        r.z = r.y + c[p].y;
        r.w = r.z + c[p].z;
        h4[p * 1024 + tid] = r;              // static prefix (coalesced)
        p4[p * 1024 + tid] = r;              // working prefix (coalesced)
        unsigned int cc[4] = {c[p].x, c[p].y, c[p].z, c[p].w};
        unsigned int rr[4] = {r.x, r.y, r.z, r.w};
        int bin0 = (p * 1024 + tid) * 4;
#pragma unroll
        for (int q = 0; q < 4; ++q) {
            if (cc[q] > 0 && rr[q] < (unsigned int)PRE_) {
                int pos = atomicAdd(&s_actn, 1);
                if (pos < ACTMAX) {
                    s_aA[pos] = rr[q];
                    s_aB[pos] = ((unsigned int)(bin0 + q) << 16) | (cc[q] & 0xffffu);
                }
            }
        }
    }
    __syncthreads();
    int n = s_actn; if (n > ACTMAX) n = ACTMAX;
    for (int i = tid; i < n; i += 1024) {
        actA[b * ACTMAX + i] = s_aA[i];
        actB[b * ACTMAX + i] = s_aB[i];
    }
    if (tid == 0) actcnt[b] = (unsigned int)n;
}

// ---- kernel 3: scatter keys of active buckets to their slot range (arrival order)
__global__ void k_scatter(const float* __restrict__ scores,
                          const unsigned int* __restrict__ hist,   // static prefix
                          unsigned int* __restrict__ prefw,        // working prefix
                          unsigned long long* __restrict__ skeys) {
    int b = blockIdx.y;
    int i = blockIdx.x * 256 + threadIdx.x;
    if (i >= N_) return;
    const float* sc = scores + (size_t)((b * 2 * A_) + A_) * HW_;
    unsigned int sb = __float_as_uint(sc[i]);
    int bin = sb_bin(sb);
    if (hist[b * NBIN + bin] < (unsigned int)PRE_) {
        unsigned int slot = atomicAdd(&prefw[b * NBIN + bin], 1u);
        if (slot < SKCAP) {
            int a = i / HW_, r = i - a * HW_;
            unsigned int n = (unsigned int)(r * A_ + a);
            skeys[b * SKCAP + slot] =
                (((unsigned long long)(~sb)) << 32) | (unsigned long long)n;
        }
    }
}

// box decode exactly in the reference op order; no FMA contraction
__device__ __forceinline__ void compute_box(int b, unsigned int n,
                                            const float* __restrict__ deltas,
                                            const float* __restrict__ im_info,
                                            float box[4]) {
#pragma clang fp contract(off)
    int a   = (int)(n % A_);
    int pos = (int)(n / A_);
    int w   = pos % W_;
    int h   = pos / W_;
    float a0 = c_anchors[a][0] + (float)(w * 16);
    float a1 = c_anchors[a][1] + (float)(h * 16);
    float a2 = c_anchors[a][2] + (float)(w * 16);
    float a3 = c_anchors[a][3] + (float)(h * 16);
    float wa  = a2 - a0 + 1.f;
    float ha  = a3 - a1 + 1.f;
    float cxa = a0 + 0.5f * wa;
    float cya = a1 + 0.5f * ha;
    int base = ((b * 4 * A_ + a * 4) * H_ + h) * W_ + w;
    const int chs = HW_;
    float dx = deltas[base];
    float dy = deltas[base + chs];
    float dw = deltas[base + 2 * chs];
    float dh = deltas[base + 3 * chs];
    float pcx = dx * wa + cxa;
    float pcy = dy * ha + cya;
    float pw  = expf(dw) * wa;
    float ph  = expf(dh) * ha;
    float x1 = pcx - 0.5f * pw;
    float y1 = pcy - 0.5f * ph;
    float x2 = pcx + 0.5f * pw;
    float y2 = pcy + 0.5f * ph;
    float imh = im_info[b * 3 + 0], imw = im_info[b * 3 + 1];
    x1 = fminf(fmaxf(x1, 0.f), imw - 1.f);
    x2 = fminf(fmaxf(x2, 0.f), imw - 1.f);
    y1 = fminf(fmaxf(y1, 0.f), imh - 1.f);
    y2 = fminf(fmaxf(y2, 0.f), imh - 1.f);
    box[0] = x1; box[1] = y1; box[2] = x2; box[3] = y2;
}

// ---- kernel 4: per-bucket exact rank-by-counting + box decode into final sorted slot
__global__ __launch_bounds__(256) void k_fixup(const unsigned long long* __restrict__ skeys,
                                               const unsigned int* __restrict__ actA,
                                               const unsigned int* __restrict__ actB,
                                               const unsigned int* __restrict__ actcnt,
                                               const float* __restrict__ deltas,
                                               const float* __restrict__ im_info,
                                               float* __restrict__ sboxes) {
    int b = blockIdx.y;
    unsigned int nact = actcnt[b];
    if (nact > ACTMAX) nact = ACTMAX;
    if (blockIdx.x >= nact) return;
    int tid = threadIdx.x;
    unsigned int start = actA[b * ACTMAX + blockIdx.x];
    unsigned int ab    = actB[b * ACTMAX + blockIdx.x];
    unsigned int cnt   = ab & 0xffffu;
    unsigned int m = cnt;
    if (start + m > SKCAP) m = SKCAP - start;
    if (m > FXCAP) m = FXCAP;
    __shared__ unsigned long long lk[FXCAP];   // 16 KB
    for (unsigned int i = tid; i < m; i += 256) lk[i] = skeys[b * SKCAP + start + i];
    __syncthreads();
    float4* sb4 = (float4*)sboxes;
    for (unsigned int e = tid; e < m; e += 256) {
        unsigned long long k = lk[e];
        unsigned int r = 0;
        for (unsigned int i = 0; i < m; ++i) r += (lk[i] < k) ? 1u : 0u;
        unsigned int pos = start + r;
        if (pos < (unsigned int)PRE_) {
            unsigned int n = (unsigned int)(k & 0xffffffffull);
            float box[4];
            compute_box(b, n, deltas, im_info, box);
            sb4[b * PRE_ + pos] = make_float4(box[0], box[1], box[2], box[3]);
        }
    }
}

__device__ __forceinline__ bool iou_gt(float4 p, float pa, float4 q, float qa) {
    float iw = fminf(p.z, q.z) - fmaxf(p.x, q.x) + 1.f;
    float ih = fminf(p.w, q.w) - fmaxf(p.y, q.y) + 1.f;
    iw = fmaxf(iw, 0.f); ih = fmaxf(ih, 0.f);
    float inter = iw * ih;
    float iou = inter / ((pa + qa) - inter);
    return iou > 0.7f;
}

// ---- kernel 5: per-block 64x64 intra-block suppression masks (fully parallel)
__global__ __launch_bounds__(64) void k_mask(const float* __restrict__ sboxes,
                                             unsigned long long* __restrict__ mask) {
    int b = blockIdx.y, blk = blockIdx.x;
    int lane = threadIdx.x;
    const float4* bb = (const float4*)sboxes + b * PRE_;
    int idx = blk * 64 + lane;
    float4 v = bb[idx < PRE_ ? idx : PRE_ - 1];
    float area = ((v.z - v.x) + 1.f) * ((v.w - v.y) + 1.f);
    unsigned long long myrow = 0ull;
    for (int i = 0; i < 64; ++i) {
        float4 p;
        p.x = __shfl(v.x, i); p.y = __shfl(v.y, i);
        p.z = __shfl(v.z, i); p.w = __shfl(v.w, i);
        float pa = __shfl(area, i);
        unsigned long long bal = __ballot((lane > i) && iou_gt(p, pa, v, area));
        if (lane == i) myrow = bal;
    }
    mask[(b * NB_ + blk) * 64 + lane] = myrow;
}

// ---- kernel 6: exact greedy NMS, pipelined (round-7 structure), phase-a unrolled x4
__global__ __launch_bounds__(1024) void k_nms(const float* __restrict__ sboxes,
                                              const unsigned long long* __restrict__ mask,
                                              float* __restrict__ out) {
    int b = blockIdx.x;
    int tid = threadIdx.x;
    int lane = tid & 63;
    int wave = tid >> 6;                     // 0..15
    __shared__ float4 s_box[POST_ + 64];
    __shared__ float  s_ar [POST_ + 64];
    __shared__ unsigned long long s_pend[2][16];
    __shared__ int s_cnt[2];
    __shared__ int s_final;
    if (tid < 32) ((unsigned long long*)s_pend)[tid] = 0ull;
    if (tid < 2) s_cnt[tid] = 0;
    if (tid == 0) s_final = 0;
    __syncthreads();

    const float4* bb = (const float4*)sboxes + b * PRE_;
    float* ob = out + b * POST_ * 5;

    // register prefetch: wave0 holds block 0 (+mask row); waves 1-15 hold block 1
    float4 vme;
    unsigned long long rowme = 0ull;
    if (wave == 0) {
        vme = bb[lane];
        rowme = mask[(b * NB_ + 0) * 64 + lane];
    } else {
        vme = bb[64 + lane];
    }

    for (int k = 0; k < NB_; ++k) {
        int Cm1 = s_cnt[(k + 1) & 1];         // kept count through block k-1
        if (Cm1 >= POST_) break;
        if (wave == 0) {
            int idx = k * 64 + lane;
            bool valid = idx < PRE_;
            float4 v = vme;
            unsigned long long row = rowme;
            if (k + 1 < NB_) {                 // prefetch block k+1
                int nidx = (k + 1) * 64 + lane;
                vme = bb[nidx < PRE_ ? nidx : PRE_ - 1];
                rowme = mask[(b * NB_ + k + 1) * 64 + lane];
            }
            float area = ((v.z - v.x) + 1.f) * ((v.w - v.y) + 1.f);
            int Cm2 = s_cnt[k & 1];           // kept count through block k-2
            bool sup = !valid;
            int kk = Cm2;                      // delta: keeps added by block k-1 (unroll 2)
            for (; kk + 1 < Cm1; kk += 2) {
                float4 k0 = s_box[kk],   k1 = s_box[kk + 1];
                float  r0 = s_ar [kk],   r1 = s_ar [kk + 1];
                sup = sup | iou_gt(v, area, k0, r0) | iou_gt(v, area, k1, r1);
            }
            for (; kk < Cm1; ++kk)
                sup = sup | iou_gt(v, area, s_box[kk], s_ar[kk]);
            unsigned long long supm = __ballot(sup);
            const unsigned long long* pnd = s_pend[k & 1];
#pragma unroll
            for (int w2 = 1; w2 < 16; ++w2) supm |= pnd[w2];
            unsigned int rlo = (unsigned int)row;
            unsigned int rhi = (unsigned int)(row >> 32);
            unsigned long long alive = ~supm;
            unsigned long long keepm = 0ull;
            while (alive) {
                int i = __builtin_ctzll(alive);     // uniform across wave 0
                keepm |= (1ull << i);
                alive &= ~(1ull << i);
                unsigned long long mlo = (unsigned int)__builtin_amdgcn_readlane((int)rlo, i);
                unsigned long long mhi = (unsigned int)__builtin_amdgcn_readlane((int)rhi, i);
                alive &= ~((mhi << 32) | mlo);
            }
            if ((keepm >> lane) & 1ull) {
                int my = Cm1 + __builtin_popcountll(keepm & ((1ull << lane) - 1ull));
                s_box[my] = v;
                s_ar [my] = area;
                if (my < POST_) {
                    ob[my * 5 + 0] = (float)b;
                    ob[my * 5 + 1] = v.x; ob[my * 5 + 2] = v.y;
                    ob[my * 5 + 3] = v.z; ob[my * 5 + 4] = v.w;
                }
            }
            if (lane == 0) {
                int nc = Cm1 + __builtin_popcountll(keepm);
                s_cnt[k & 1] = nc;
                s_final = nc;
            }
        } else if (k + 1 < NB_) {
            // phase-a for block k+1 vs kept[0..Cm1), stride 15, UNROLLED x4
            int jdx = (k + 1) * 64 + lane;
            bool valid2 = jdx < PRE_;
            float4 v2 = vme;
            if (k + 2 < NB_) {                 // prefetch block k+2
                int nj = (k + 2) * 64 + lane;
                vme = bb[nj < PRE_ ? nj : PRE_ - 1];
            }
            float area2 = ((v2.z - v2.x) + 1.f) * ((v2.w - v2.y) + 1.f);
            bool sup2 = !valid2;
            int kk = wave - 1;
            for (; kk + 45 < Cm1; kk += 60) {   // 4 strided entries per pass
                float4 k0 = s_box[kk],      k1 = s_box[kk + 15];
                float4 k2 = s_box[kk + 30], k3 = s_box[kk + 45];
                float  r0 = s_ar [kk],      r1 = s_ar [kk + 15];
                float  r2 = s_ar [kk + 30], r3 = s_ar [kk + 45];
                sup2 = sup2 | iou_gt(v2, area2, k0, r0) | iou_gt(v2, area2, k1, r1)
                            | iou_gt(v2, area2, k2, r2) | iou_gt(v2, area2, k3, r3);
            }
            for (; kk < Cm1; kk += 15)
                sup2 = sup2 | iou_gt(v2, area2, s_box[kk], s_ar[kk]);
            unsigned long long bal = __ballot(sup2);
            if (lane == 0) s_pend[(k + 1) & 1][wave] = bal;
        }
        __syncthreads();
    }
    __syncthreads();
    int kept = s_final;
    int start = kept < POST_ ? kept : POST_;
    for (int r = start + tid; r < POST_; r += 1024) {
        ob[r * 5 + 0] = (float)b;
        ob[r * 5 + 1] = 0.f; ob[r * 5 + 2] = 0.f;
        ob[r * 5 + 3] = 0.f; ob[r * 5 + 4] = 0.f;
    }
}

extern "C" void kernel_launch(void* const* d_in, const int* in_sizes, int n_in,
                              void* d_out, int out_size, void* d_ws, size_t ws_size,
                              hipStream_t stream) {
    const float* scores  = (const float*)d_in[0];
    const float* deltas  = (const float*)d_in[1];
    const float* im_info = (const float*)d_in[2];
    float* out = (float*)d_out;

    // workspace layout. maskb OVERLAPS hist (hist dead after k_scatter; k_mask later).
    char* ws = (char*)d_ws;
    unsigned int*       hist    = (unsigned int*)      (ws);             // 262,144
    unsigned long long* maskb   = (unsigned long long*)(ws);             // 192,512 (reuse)
    unsigned int*       prefw   = (unsigned int*)      (ws + 262144);    // 262,144
    unsigned long long* skeys   = (unsigned long long*)(ws + 524288);    // 262,144
    unsigned int*       actA    = (unsigned int*)      (ws + 786432);    //   4,096
    unsigned int*       actB    = (unsigned int*)      (ws + 790528);    //   4,096
    unsigned int*       actcnt  = (unsigned int*)      (ws + 794624);    //      32
    float*              sbx     = (float*)             (ws + 794656);    // 384,000

    hipMemsetAsync(hist, 0, B_ * NBIN * sizeof(unsigned int), stream);

    dim3 g2d((N_ + 255) / 256, B_);
    k_hist<<<g2d, 256, 0, stream>>>(scores, hist);
    k_prefix<<<B_, 1024, 0, stream>>>(hist, prefw, actA, actB, actcnt);
    k_scatter<<<g2d, 256, 0, stream>>>(scores, hist, prefw, skeys);
    dim3 fgrid(ACTMAX, B_);
    k_fixup<<<fgrid, 256, 0, stream>>>(skeys, actA, actB, actcnt, deltas, im_info, sbx);
    dim3 mgrid(NB_, B_);
    k_mask<<<mgrid, 64, 0, stream>>>(sbx, maskb);
    k_nms<<<B_, 1024, 0, stream>>>(sbx, maskb, out);
}